// Round 16
// baseline (738.944 us; speedup 1.0000x reference)
//
#include <hip/hip_runtime.h>
#include <math.h>

#define B_TOTAL  262144
#define ROWS     64
#define NWG      (B_TOTAL/ROWS)   // 4096
#define NTHR     512
#define PI_F     3.14159265358979323846f
#define NORM_R   (500.0f/150000.0f)

typedef float  f32x4  __attribute__((ext_vector_type(4)));
typedef short  bf16x8 __attribute__((ext_vector_type(8)));

// ---- ws layout (ushorts): pre-swizzled LDS images ----
#define GRU_SLAB 24576                 // 48KB: [r|z|n] x (256 cols x 64B) at one kb
#define OFF_GRU  0                     // 11 slabs (kb 0..10)
#define OFF_W1   (11*GRU_SLAB)         // 270336: 8 kb x 8192 (16KB each)
#define OFF_W2   (OFF_W1 + 8*8192)     // 335872: 8 kb x 4096 (8KB each, 128 cols)
#define OFF_W3   (OFF_W2 + 8*4096)     // 368640: 4 kb x 8192 (16KB, cols>=162 zero)
#define W_TOTAL  (OFF_W3 + 4*8192)     // 401408 ushorts = 784KB

// ---- LDS layout (bytes) ----
#define LDS_RBF2  0                    // Rb [64][104]u16 (13.3KB) -> F2 [64][136]u16 (17KB)
#define LDS_HB    17408                // Hb [64][256] bf16 swizzled: hx -> h_ln -> f1acts
#define LDS_STG   (LDS_HB + 32768)     // 50176: 2 x 48KB slab dbuf (buf1 also input scratch)
#define LDS_XMC   (LDS_STG + 2*49152)  // 148480: [64][6] f32
#define LDS_LNS   (LDS_XMC + 1536)     // 150016: LN partials [64][8][2] f32 = 4KB
#define LDS_TOTAL (LDS_LNS + 4096)     // 154112

#define WAIT_VM0 asm volatile("s_waitcnt vmcnt(0)" ::: "memory")
#define BARv     __builtin_amdgcn_s_barrier()

__device__ __forceinline__ ushort f2bf(float f){
    union { float f; unsigned u; } v; v.f = f;
    unsigned r = v.u + 0x7FFFu + ((v.u >> 16) & 1u);
    return (ushort)(r >> 16);
}
__device__ __forceinline__ float b2f(ushort u){
    union { unsigned u; float f; } v; v.u = ((unsigned)u) << 16;
    return v.f;
}
__device__ __forceinline__ float sigm(float x){ return 1.0f/(1.0f+__expf(-x)); }
__device__ __forceinline__ float tanh_(float x){ return 1.0f - 2.0f/(__expf(2.0f*x)+1.0f); }
__device__ __forceinline__ int swzb(int row, int k){          // Hb [64][256] bf16 16B-XOR
    return ((row<<9) + (k<<1)) ^ ((row&7)<<4);
}
// weight-frag read from slab: W[col][k-chunk lk], slot-XOR for bank spread
__device__ __forceinline__ bf16x8 rdW(const char* gb, int col, int lk){
    int slot = lk ^ ((col >> 1) & 3);
    return *(const bf16x8*)(gb + col*64 + slot*16);
}
// fully-linear slab staging: ws image -> LDS, contiguous on both sides
template<int N>
__device__ __forceinline__ void stage_lin(const ushort* src, char* dst, int w, int lane){
    #pragma unroll
    for (int i = 0; i < N; ++i) {
        __builtin_amdgcn_global_load_lds(
            (const __attribute__((address_space(1))) void*)(src + (size_t)(i*512 + w*64 + lane)*8),
            (__attribute__((address_space(3))) void*)(dst + i*8192 + w*1024),
            16, 0, 0);
    }
}
// f1-style cluster (nq/mh layout): 4 col-frags x 2 row-frags
__device__ __forceinline__ void mm4(const char* gb, int colbase, int lr, int lk,
                                    bf16x8 a0, bf16x8 a1, f32x4 acc[2][4]){
    #pragma unroll
    for (int j = 0; j < 4; ++j) {
        bf16x8 wf = rdW(gb, colbase + j*16 + lr, lk);
        acc[0][j] = __builtin_amdgcn_mfma_f32_16x16x32_bf16(wf, a0, acc[0][j], 0,0,0);
        acc[1][j] = __builtin_amdgcn_mfma_f32_16x16x32_bf16(wf, a1, acc[1][j], 0,0,0);
    }
}
// GRU cluster (8-way col split): 2 col-frags x 4 row-frags, each wf read once
__device__ __forceinline__ void mmG(const char* gb, int colbase, int lr, int lk,
                                    const bf16x8 a[4], f32x4 acc[4][2]){
    #pragma unroll
    for (int j = 0; j < 2; ++j) {
        bf16x8 wf = rdW(gb, colbase + j*16 + lr, lk);
        #pragma unroll
        for (int i = 0; i < 4; ++i)
            acc[i][j] = __builtin_amdgcn_mfma_f32_16x16x32_bf16(wf, a[i], acc[i][j], 0,0,0);
    }
}

__global__ void prep_weights(const float* __restrict__ W_ih, const float* __restrict__ W_hh,
                             const float* __restrict__ W1, const float* __restrict__ W2,
                             const float* __restrict__ W3, ushort* __restrict__ ws)
{
    int id = blockIdx.x*256 + threadIdx.x;
    if (id >= W_TOTAL) return;
    float v = 0.0f;
    if (id < OFF_W1) {                       // GRU slabs: [gate][col][slot][e]
        int slab = id / GRU_SLAB, u = id % GRU_SLAB;
        int gate = u >> 13, u2 = u & 8191;
        int col = u2 >> 5, v5 = u2 & 31, slot = v5 >> 3, e = v5 & 7;
        int kq = slot ^ ((col >> 1) & 3);
        int k = slab*32 + kq*8 + e;
        int rowz = gate*256 + col;
        v = (k < 73) ? W_ih[rowz*73 + k] : ((k < 96) ? 0.0f : W_hh[rowz*256 + (k-96)]);
    } else if (id < OFF_W2) {                // W1: 8 x 16KB kb-slabs
        int t = id - OFF_W1, kb = t >> 13, u2 = t & 8191;
        int col = u2 >> 5, v5 = u2 & 31, slot = v5 >> 3, e = v5 & 7;
        int kq = slot ^ ((col >> 1) & 3);
        v = W1[col*256 + kb*32 + kq*8 + e];
    } else if (id < OFF_W3) {                // W2: 8 x 8KB kb-slabs (128 cols)
        int t = id - OFF_W2, kb = t >> 12, u2 = t & 4095;
        int col = u2 >> 5, v5 = u2 & 31, slot = v5 >> 3, e = v5 & 7;
        int kq = slot ^ ((col >> 1) & 3);
        v = W2[col*256 + kb*32 + kq*8 + e];
    } else {                                 // W3: 4 x 16KB kb-slabs, cols>=162 zero
        int t = id - OFF_W3, kb = t >> 13, u2 = t & 8191;
        int col = u2 >> 5, v5 = u2 & 31, slot = v5 >> 3, e = v5 & 7;
        int kq = slot ^ ((col >> 1) & 3);
        int k = kb*32 + kq*8 + e;
        v = (col < 162) ? W3[col*128 + k] : 0.0f;
    }
    ws[id] = f2bf(v);
}

__global__ __launch_bounds__(NTHR, 1) void knet_mfma(
    const float* __restrict__ meas, const float* __restrict__ mask,
    const float* __restrict__ dt,   const float* __restrict__ baselines,
    const float* __restrict__ x_prev, const float* __restrict__ hx,
    const float* __restrict__ b_ih, const float* __restrict__ b_hh,
    const float* __restrict__ ln_g, const float* __restrict__ ln_b,
    const float* __restrict__ b1,   const float* __restrict__ b2,
    const float* __restrict__ b3,
    const ushort* __restrict__ ws,
    float* __restrict__ out)
{
    extern __shared__ char smem[];
    ushort* Rbu  = (ushort*)(smem + LDS_RBF2);   // Rb then F2
    char*   Hb   = smem + LDS_HB;
    char*   STG  = smem + LDS_STG;
    float*  xmc  = (float*)(smem + LDS_XMC);
    float*  lnscr= (float*)(smem + LDS_LNS);

    const int tid  = threadIdx.x;
    const int w    = __builtin_amdgcn_readfirstlane(tid >> 6);
    const int nq   = w & 3;
    const int mh   = w >> 2;
    const int lane = tid & 63;
    const int lr   = lane & 15;
    const int lk   = lane >> 4;
    const int lk8  = lk * 8;
    const int row0 = blockIdx.x * ROWS;
    const int mrow = mh*32 + lr;
    const int cw   = w * 32;      // GRU: this wave's col base
    float* hout = out + (size_t)B_TOTAL*6;

    // prologue: slab 0 -> buf0 (linear copy)
    stage_lin<6>(ws + OFF_GRU, STG, w, lane);

    // ====== coalesced input staging -> buf1 scratch (f32) ======
    float* scr = (float*)(STG + 49152);
    {
        const size_t m0 = (size_t)row0*27;
        for (int i = tid; i < 1728; i += NTHR) scr[i]        = meas[m0 + i];
        for (int i = tid; i < 1728; i += NTHR) scr[1728 + i] = mask[m0 + i];
        const size_t b0 = (size_t)row0*12;
        for (int i = tid; i < 768; i += NTHR)  scr[3456 + i] = baselines[b0 + i];
        if (tid < 384) scr[4224 + tid] = x_prev[(size_t)row0*6 + tid];
        if (tid < 64)  scr[4608 + tid] = dt[row0 + tid];
        const size_t hbase = (size_t)row0 * 256;
        #pragma unroll
        for (int ii = 0; ii < 4; ++ii) {
            int cid = tid + ii*NTHR;
            int r  = cid >> 5;
            int k0 = (cid & 31) << 3;
            const float4* p = (const float4*)(hx + hbase + (size_t)r*256 + k0);
            float4 u = p[0], v2 = p[1];
            bf16x8 o;
            o[0]=(short)f2bf(u.x);  o[1]=(short)f2bf(u.y);  o[2]=(short)f2bf(u.z);  o[3]=(short)f2bf(u.w);
            o[4]=(short)f2bf(v2.x); o[5]=(short)f2bf(v2.y); o[6]=(short)f2bf(v2.z); o[7]=(short)f2bf(v2.w);
            *(bf16x8*)(Hb + swzb(r, k0)) = o;
        }
    }
    __syncthreads();

    // ====== geometry from scratch -> Rb, xmc ======
    if (w < 4) {
        const int row = lane;
        const float dtv = scr[4608 + row];
        const float dts = dtv * NORM_R;
        float xp[6], xm[6];
        #pragma unroll
        for (int s = 0; s < 6; ++s) xp[s] = scr[4224 + row*6 + s];
        xm[0] = xp[0] + dts*xp[1]; xm[1] = xp[1];
        xm[2] = xp[2] + dts*xp[3]; xm[3] = xp[3];
        xm[4] = xp[4] + dts*xp[5]; xm[5] = xp[5];
        if (w < 3) {
            float xr[6];
            #pragma unroll
            for (int s = 0; s < 6; ++s) {
                float b = (w == 0) ? 0.0f : scr[3456 + row*12 + (w-1)*6 + s];
                xr[s] = xm[s] - b;
            }
            float rxy = sqrtf(xr[0]*xr[0] + xr[2]*xr[2] + 1e-9f);
            float azv = atan2f(xr[2], xr[0]) * (1.0f/PI_F);
            float elv = atan2f(xr[4], rxy)   * (1.0f/PI_F);
            float rrv = sqrtf(xr[0]*xr[0] + xr[2]*xr[2] + xr[4]*xr[4] + 1e-9f);
            float y[9] = {azv, elv, rrv, azv, elv, 0.0f, azv, 0.0f, 0.0f};
            const bool ang[9] = {true,true,false,true,true,false,true,false,false};
            #pragma unroll
            for (int i = 0; i < 9; ++i) {
                int m = w*9 + i;
                float ms = scr[1728 + row*27 + m];
                float v  = scr[row*27 + m] - y[i];
                if (ang[i]) v = v - 2.0f*rintf(v*0.5f);
                v *= ms;
                Rbu[row*104 + m]      = f2bf(v);
                Rbu[row*104 + 27 + m] = f2bf(ms);
            }
        } else {
            Rbu[row*104 + 54] = f2bf(dtv);
            #pragma unroll
            for (int s = 0; s < 6; ++s) Rbu[row*104 + 55 + s] = f2bf(xm[s]);
            #pragma unroll
            for (int q = 0; q < 12; ++q) Rbu[row*104 + 61 + q] = f2bf(scr[3456 + row*12 + q]);
            #pragma unroll
            for (int k = 73; k < 96; ++k) Rbu[row*104 + k] = 0;
            #pragma unroll
            for (int s = 0; s < 6; ++s) xmc[row*6 + s] = xm[s];
        }
    }
    __syncthreads();

    // ====== GRU: 11 x 48KB phases, 8-way col split (each wf read once) ======
    f32x4 ar[4][2], az[4][2], agi[4][2], agh[4][2];
    #pragma unroll
    for (int i = 0; i < 4; ++i)
        #pragma unroll
        for (int j = 0; j < 2; ++j) {
            ar[i][j]=(f32x4){0,0,0,0}; az[i][j]=(f32x4){0,0,0,0};
            agi[i][j]=(f32x4){0,0,0,0}; agh[i][j]=(f32x4){0,0,0,0};
        }
    #pragma unroll
    for (int kb = 0; kb < 11; ++kb) {
        WAIT_VM0; BARv;
        if (kb < 10) stage_lin<6>(ws + OFF_GRU + (kb+1)*GRU_SLAB, STG + ((kb+1)&1)*49152, w, lane);
        else         stage_lin<6>(ws + OFF_W1,                    STG + 49152,            w, lane); // p11 -> buf1
        const char* sb = STG + (kb&1)*49152;
        bf16x8 a[4];
        if (kb < 3) {
            #pragma unroll
            for (int i = 0; i < 4; ++i)
                a[i] = *(const bf16x8*)(Rbu + (i*16 + lr)*104 + kb*32 + lk8);
        } else {
            #pragma unroll
            for (int i = 0; i < 4; ++i)
                a[i] = *(const bf16x8*)(Hb + swzb(i*16 + lr, (kb-3)*32 + lk8));
        }
        __builtin_amdgcn_s_setprio(1);
        mmG(sb,         cw, lr, lk, a, ar);
        mmG(sb + 16384, cw, lr, lk, a, az);
        if (kb < 3) mmG(sb + 32768, cw, lr, lk, a, agi);
        else        mmG(sb + 32768, cw, lr, lk, a, agh);
        __builtin_amdgcn_s_setprio(0);
    }

    // ====== GRU epilogue: gates -> h_new (regs) + global store + LN partials ======
    f32x4 hnv[4][2];
    float lsum[4] = {0,0,0,0}, lsq[4] = {0,0,0,0};
    #pragma unroll
    for (int j = 0; j < 2; ++j) {
        const int c0 = cw + j*16 + lk*4;
        f32x4 bir = *(const f32x4*)(b_ih + c0),        bhr = *(const f32x4*)(b_hh + c0);
        f32x4 biz = *(const f32x4*)(b_ih + 256 + c0),  bhz = *(const f32x4*)(b_hh + 256 + c0);
        f32x4 bin_= *(const f32x4*)(b_ih + 512 + c0),  bhn = *(const f32x4*)(b_hh + 512 + c0);
        #pragma unroll
        for (int i = 0; i < 4; ++i) {
            const int row = i*16 + lr;
            uint2 hxd = *(const uint2*)(Hb + swzb(row, c0));
            float hx_[4] = { b2f((ushort)(hxd.x & 0xffffu)), b2f((ushort)(hxd.x >> 16)),
                             b2f((ushort)(hxd.y & 0xffffu)), b2f((ushort)(hxd.y >> 16)) };
            f32x4 hn4;
            #pragma unroll
            for (int e = 0; e < 4; ++e) {
                float rg = sigm(ar[i][j][e] + bir[e] + bhr[e]);
                float zg = sigm(az[i][j][e] + biz[e] + bhz[e]);
                float ng = tanh_(agi[i][j][e] + bin_[e] + rg*(agh[i][j][e] + bhn[e]));
                float hn = (1.0f - zg)*ng + zg*hx_[e];
                hn4[e] = hn;
                lsum[i] += hn; lsq[i] += hn*hn;
            }
            hnv[i][j] = hn4;
            float4 st = { hn4[0], hn4[1], hn4[2], hn4[3] };
            *(float4*)(hout + (size_t)(row0+row)*256 + c0) = st;
        }
    }
    #pragma unroll
    for (int i = 0; i < 4; ++i) {
        lsum[i] += __shfl_xor(lsum[i], 16); lsum[i] += __shfl_xor(lsum[i], 32);
        lsq[i]  += __shfl_xor(lsq[i], 16);  lsq[i]  += __shfl_xor(lsq[i], 32);
    }
    if (lk == 0) {
        #pragma unroll
        for (int i = 0; i < 4; ++i) {
            const int row = i*16 + lr;
            lnscr[row*16 + w*2 + 0] = lsum[i];
            lnscr[row*16 + w*2 + 1] = lsq[i];
        }
    }
    __syncthreads();

    // ====== LayerNorm apply (regs -> Hb h_ln) ======
    {
        float mu[4], rstd[4];
        #pragma unroll
        for (int i = 0; i < 4; ++i) {
            const int row = i*16 + lr;
            float s = 0, q = 0;
            #pragma unroll
            for (int ww = 0; ww < 8; ++ww) { s += lnscr[row*16 + ww*2]; q += lnscr[row*16 + ww*2 + 1]; }
            mu[i] = s * (1.0f/256.0f);
            rstd[i] = rsqrtf(q*(1.0f/256.0f) - mu[i]*mu[i] + 1e-5f);
        }
        #pragma unroll
        for (int j = 0; j < 2; ++j) {
            const int c0 = cw + j*16 + lk*4;
            f32x4 g4 = *(const f32x4*)(ln_g + c0);
            f32x4 b4 = *(const f32x4*)(ln_b + c0);
            #pragma unroll
            for (int i = 0; i < 4; ++i) {
                const int row = i*16 + lr;
                float v0 = (hnv[i][j][0]-mu[i])*rstd[i]*g4[0] + b4[0];
                float v1 = (hnv[i][j][1]-mu[i])*rstd[i]*g4[1] + b4[1];
                float v2 = (hnv[i][j][2]-mu[i])*rstd[i]*g4[2] + b4[2];
                float v3 = (hnv[i][j][3]-mu[i])*rstd[i]*g4[3] + b4[3];
                uint2 o;
                o.x = (unsigned)f2bf(v0) | ((unsigned)f2bf(v1) << 16);
                o.y = (unsigned)f2bf(v2) | ((unsigned)f2bf(v3) << 16);
                *(uint2*)(Hb + swzb(row, c0)) = o;
            }
        }
    }
    __syncthreads();

    // ====== f1 = relu(W1 h_ln + b1): 3 phases (kb 0-2, 3-5, 6-7) ======
    f32x4 c2[2][4];
    #pragma unroll
    for (int i = 0; i < 2; ++i)
        #pragma unroll
        for (int j = 0; j < 4; ++j) c2[i][j] = (f32x4){0,0,0,0};
    // p11 (buf1): kb 0..2
    WAIT_VM0; BARv;
    stage_lin<6>(ws + OFF_W1 + 3*8192, STG, w, lane);            // p12 -> buf0
    {
        const char* sb = STG + 49152;
        #pragma unroll
        for (int kb = 0; kb < 3; ++kb) {
            bf16x8 a0 = *(const bf16x8*)(Hb + swzb(mrow,    kb*32 + lk8));
            bf16x8 a1 = *(const bf16x8*)(Hb + swzb(mrow+16, kb*32 + lk8));
            __builtin_amdgcn_s_setprio(1);
            mm4(sb + kb*16384, nq*64, lr, lk, a0, a1, c2);
            __builtin_amdgcn_s_setprio(0);
        }
    }
    // p12 (buf0): kb 3..5
    WAIT_VM0; BARv;
    stage_lin<4>(ws + OFF_W1 + 6*8192, STG + 49152, w, lane);    // p13 -> buf1
    {
        const char* sb = STG;
        #pragma unroll
        for (int kb = 3; kb < 6; ++kb) {
            bf16x8 a0 = *(const bf16x8*)(Hb + swzb(mrow,    kb*32 + lk8));
            bf16x8 a1 = *(const bf16x8*)(Hb + swzb(mrow+16, kb*32 + lk8));
            __builtin_amdgcn_s_setprio(1);
            mm4(sb + (kb-3)*16384, nq*64, lr, lk, a0, a1, c2);
            __builtin_amdgcn_s_setprio(0);
        }
    }
    // p13 (buf1): kb 6..7
    WAIT_VM0; BARv;
    stage_lin<4>(ws + OFF_W2, STG, w, lane);                     // p14 -> buf0
    {
        const char* sb = STG + 49152;
        #pragma unroll
        for (int kb = 6; kb < 8; ++kb) {
            bf16x8 a0 = *(const bf16x8*)(Hb + swzb(mrow,    kb*32 + lk8));
            bf16x8 a1 = *(const bf16x8*)(Hb + swzb(mrow+16, kb*32 + lk8));
            __builtin_amdgcn_s_setprio(1);
            mm4(sb + (kb-6)*16384, nq*64, lr, lk, a0, a1, c2);
            __builtin_amdgcn_s_setprio(0);
        }
    }
    __syncthreads();   // all h_ln reads done before f1-act overwrite of Hb
    #pragma unroll
    for (int j = 0; j < 4; ++j) {
        const int c0 = nq*64 + j*16 + lk*4;
        f32x4 b4 = *(const f32x4*)(b1 + c0);
        #pragma unroll
        for (int i = 0; i < 2; ++i) {
            const int row = mh*32 + i*16 + lr;
            uint2 o;
            o.x = (unsigned)f2bf(fmaxf(c2[i][j][0]+b4[0],0.f)) | ((unsigned)f2bf(fmaxf(c2[i][j][1]+b4[1],0.f)) << 16);
            o.y = (unsigned)f2bf(fmaxf(c2[i][j][2]+b4[2],0.f)) | ((unsigned)f2bf(fmaxf(c2[i][j][3]+b4[3],0.f)) << 16);
            *(uint2*)(Hb + swzb(row, c0)) = o;
        }
    }
    __syncthreads();

    // ====== f2 = relu(W2 f1 + b2): 2 phases ======
    f32x4 c3[2][2];
    #pragma unroll
    for (int i = 0; i < 2; ++i)
        #pragma unroll
        for (int j = 0; j < 2; ++j) c3[i][j] = (f32x4){0,0,0,0};
    // p14 (buf0): kb 0..3
    WAIT_VM0; BARv;
    stage_lin<4>(ws + OFF_W2 + 4*4096, STG + 49152, w, lane);    // p15 -> buf1
    {
        const char* sb = STG;
        #pragma unroll
        for (int kb = 0; kb < 4; ++kb) {
            bf16x8 a0 = *(const bf16x8*)(Hb + swzb(mrow,    kb*32 + lk8));
            bf16x8 a1 = *(const bf16x8*)(Hb + swzb(mrow+16, kb*32 + lk8));
            __builtin_amdgcn_s_setprio(1);
            #pragma unroll
            for (int j = 0; j < 2; ++j) {
                bf16x8 wf = rdW(sb + kb*8192, nq*32 + j*16 + lr, lk);
                c3[0][j] = __builtin_amdgcn_mfma_f32_16x16x32_bf16(wf, a0, c3[0][j], 0,0,0);
                c3[1][j] = __builtin_amdgcn_mfma_f32_16x16x32_bf16(wf, a1, c3[1][j], 0,0,0);
            }
            __builtin_amdgcn_s_setprio(0);
        }
    }
    // p15 (buf1): kb 4..7
    WAIT_VM0; BARv;
    stage_lin<4>(ws + OFF_W3, STG, w, lane);                     // p16 -> buf0
    {
        const char* sb = STG + 49152;
        #pragma unroll
        for (int kb = 4; kb < 8; ++kb) {
            bf16x8 a0 = *(const bf16x8*)(Hb + swzb(mrow,    kb*32 + lk8));
            bf16x8 a1 = *(const bf16x8*)(Hb + swzb(mrow+16, kb*32 + lk8));
            __builtin_amdgcn_s_setprio(1);
            #pragma unroll
            for (int j = 0; j < 2; ++j) {
                bf16x8 wf = rdW(sb + (kb-4)*8192, nq*32 + j*16 + lr, lk);
                c3[0][j] = __builtin_amdgcn_mfma_f32_16x16x32_bf16(wf, a0, c3[0][j], 0,0,0);
                c3[1][j] = __builtin_amdgcn_mfma_f32_16x16x32_bf16(wf, a1, c3[1][j], 0,0,0);
            }
            __builtin_amdgcn_s_setprio(0);
        }
    }
    // preload innov for einsum (Rb dies to F2 overlay next)
    f32x4 iv[2][3];
    #pragma unroll
    for (int j = 0; j < 3; ++j) {
        #pragma unroll
        for (int i = 0; i < 2; ++i) {
            const int row = mh*32 + i*16 + lr;
            #pragma unroll
            for (int e = 0; e < 4; ++e) {
                int col = nq*48 + j*16 + lk*4 + e;
                int m = col - 27*(col/27);
                iv[i][j][e] = b2f(Rbu[row*104 + m]);
            }
        }
    }
    __syncthreads();   // innov reads done before F2 writes over Rb
    #pragma unroll
    for (int j = 0; j < 2; ++j) {
        const int c0 = nq*32 + j*16 + lk*4;
        f32x4 b4 = *(const f32x4*)(b2 + c0);
        #pragma unroll
        for (int i = 0; i < 2; ++i) {
            const int row = mh*32 + i*16 + lr;
            uint2 o;
            o.x = (unsigned)f2bf(fmaxf(c3[i][j][0]+b4[0],0.f)) | ((unsigned)f2bf(fmaxf(c3[i][j][1]+b4[1],0.f)) << 16);
            o.y = (unsigned)f2bf(fmaxf(c3[i][j][2]+b4[2],0.f)) | ((unsigned)f2bf(fmaxf(c3[i][j][3]+b4[3],0.f)) << 16);
            *(uint2*)((char*)Rbu + row*272 + c0*2) = o;      // F2 [64][136] u16
        }
    }
    __syncthreads();

    // ====== K = clip(W3 f2 + b3): 2 phases + einsum ======
    f32x4 c4[2][3];
    #pragma unroll
    for (int i = 0; i < 2; ++i)
        #pragma unroll
        for (int j = 0; j < 3; ++j) c4[i][j] = (f32x4){0,0,0,0};
    // p16 (buf0): kb 0,1
    WAIT_VM0; BARv;
    stage_lin<4>(ws + OFF_W3 + 2*8192, STG + 49152, w, lane);    // p17 -> buf1
    {
        const char* sb = STG;
        #pragma unroll
        for (int kb = 0; kb < 2; ++kb) {
            bf16x8 a0 = *(const bf16x8*)((char*)Rbu + (mrow     )*272 + (kb*32 + lk8)*2);
            bf16x8 a1 = *(const bf16x8*)((char*)Rbu + (mrow + 16)*272 + (kb*32 + lk8)*2);
            __builtin_amdgcn_s_setprio(1);
            #pragma unroll
            for (int j = 0; j < 3; ++j) {
                bf16x8 wf = rdW(sb + kb*16384, nq*48 + j*16 + lr, lk);
                c4[0][j] = __builtin_amdgcn_mfma_f32_16x16x32_bf16(wf, a0, c4[0][j], 0,0,0);
                c4[1][j] = __builtin_amdgcn_mfma_f32_16x16x32_bf16(wf, a1, c4[1][j], 0,0,0);
            }
            __builtin_amdgcn_s_setprio(0);
        }
    }
    // p17 (buf1): kb 2,3
    WAIT_VM0; BARv;
    {
        const char* sb = STG + 49152;
        #pragma unroll
        for (int kb = 2; kb < 4; ++kb) {
            bf16x8 a0 = *(const bf16x8*)((char*)Rbu + (mrow     )*272 + (kb*32 + lk8)*2);
            bf16x8 a1 = *(const bf16x8*)((char*)Rbu + (mrow + 16)*272 + (kb*32 + lk8)*2);
            __builtin_amdgcn_s_setprio(1);
            #pragma unroll
            for (int j = 0; j < 3; ++j) {
                bf16x8 wf = rdW(sb + (kb-2)*16384, nq*48 + j*16 + lr, lk);
                c4[0][j] = __builtin_amdgcn_mfma_f32_16x16x32_bf16(wf, a0, c4[0][j], 0,0,0);
                c4[1][j] = __builtin_amdgcn_mfma_f32_16x16x32_bf16(wf, a1, c4[1][j], 0,0,0);
            }
            __builtin_amdgcn_s_setprio(0);
        }
    }
    #pragma unroll
    for (int j = 0; j < 3; ++j) {
        #pragma unroll
        for (int i = 0; i < 2; ++i) {
            const int row = mh*32 + i*16 + lr;
            #pragma unroll
            for (int e = 0; e < 4; ++e) {
                int col = nq*48 + j*16 + lk*4 + e;
                if (col < 162) {
                    int s = col / 27;
                    float K = fminf(fmaxf(c4[i][j][e] + b3[col], -3.0f), 3.0f);
                    atomicAdd(&xmc[row*6 + s], K * iv[i][j][e]);
                }
            }
        }
    }
    __syncthreads();

    for (int t = tid; t < ROWS*6; t += NTHR) {
        int row = t / 6, s = t - row*6;
        float v = fminf(fmaxf(xmc[t], -5.0f), 5.0f);
        out[(size_t)(row0+row)*6 + s] = v;
    }
}

extern "C" void kernel_launch(void* const* d_in, const int* in_sizes, int n_in,
                              void* d_out, int out_size, void* d_ws, size_t ws_size,
                              hipStream_t stream) {
    const float* meas      = (const float*)d_in[0];
    const float* mask      = (const float*)d_in[1];
    const float* dtv       = (const float*)d_in[2];
    const float* baselines = (const float*)d_in[3];
    const float* x_prev    = (const float*)d_in[4];
    const float* hx        = (const float*)d_in[5];
    const float* W_ih      = (const float*)d_in[6];
    const float* W_hh      = (const float*)d_in[7];
    const float* b_ih      = (const float*)d_in[8];
    const float* b_hh      = (const float*)d_in[9];
    const float* ln_g      = (const float*)d_in[10];
    const float* ln_b      = (const float*)d_in[11];
    const float* W1        = (const float*)d_in[12];
    const float* b1        = (const float*)d_in[13];
    const float* W2        = (const float*)d_in[14];
    const float* b2        = (const float*)d_in[15];
    const float* W3        = (const float*)d_in[16];
    const float* b3        = (const float*)d_in[17];
    ushort* wsb = (ushort*)d_ws;
    float* outp = (float*)d_out;

    prep_weights<<<(W_TOTAL + 255)/256, 256, 0, stream>>>(W_ih, W_hh, W1, W2, W3, wsb);
    knet_mfma<<<NWG, NTHR, LDS_TOTAL, stream>>>(
        meas, mask, dtv, baselines, x_prev, hx,
        b_ih, b_hh, ln_g, ln_b, b1, b2, b3, wsb, outp);
}

// Round 17
// 692.417 us; speedup vs baseline: 1.0672x; 1.0672x over previous
//
#include <hip/hip_runtime.h>
#include <math.h>

#define B_TOTAL  262144
#define ROWS     64
#define NWG      (B_TOTAL/ROWS)   // 4096
#define NTHR     512
#define PI_F     3.14159265358979323846f
#define NORM_R   (500.0f/150000.0f)

typedef float  f32x4  __attribute__((ext_vector_type(4)));
typedef short  bf16x8 __attribute__((ext_vector_type(8)));

// ---- ws layout (ushorts): pre-swizzled LDS images ----
#define GRU_SLAB 24576                 // 48KB: [r|z|n] x (256 cols x 64B) at one kb
#define OFF_GRU  0                     // 11 slabs (kb 0..10)
#define OFF_W1   (11*GRU_SLAB)         // 270336: 8 kb x 8192 (16KB each)
#define OFF_W2   (OFF_W1 + 8*8192)     // 335872: 8 kb x 4096 (8KB each, 128 cols)
#define OFF_W3   (OFF_W2 + 8*4096)     // 368640: 4 kb x 8192 (16KB, cols>=162 zero)
#define W_TOTAL  (OFF_W3 + 4*8192)     // 401408 ushorts = 784KB

// ---- LDS layout (bytes) ----
#define LDS_RBF2  0                    // Rb [64][104]u16 (13.3KB) -> F2 [64][136]u16 (17KB)
#define LDS_HB    17408                // Hb [64][256] bf16 swizzled: hx -> h_ln -> f1acts
#define LDS_STG   (LDS_HB + 32768)     // 50176: 2 x 48KB slab dbuf (buf1 also input scratch)
#define LDS_XMC   (LDS_STG + 2*49152)  // 148480: [64][6] f32
#define LDS_LNS   (LDS_XMC + 1536)     // 150016: LN partials [64][4][2] f32
#define LDS_TOTAL (LDS_LNS + 2048)     // 152064

#define WAIT_VM0 asm volatile("s_waitcnt vmcnt(0)" ::: "memory")
#define BARv     __builtin_amdgcn_s_barrier()

__device__ __forceinline__ ushort f2bf(float f){
    union { float f; unsigned u; } v; v.f = f;
    unsigned r = v.u + 0x7FFFu + ((v.u >> 16) & 1u);
    return (ushort)(r >> 16);
}
__device__ __forceinline__ float b2f(ushort u){
    union { unsigned u; float f; } v; v.u = ((unsigned)u) << 16;
    return v.f;
}
__device__ __forceinline__ float sigm(float x){ return 1.0f/(1.0f+__expf(-x)); }
__device__ __forceinline__ float tanh_(float x){ return 1.0f - 2.0f/(__expf(2.0f*x)+1.0f); }
__device__ __forceinline__ int swzb(int row, int k){          // Hb [64][256] bf16 16B-XOR
    return ((row<<9) + (k<<1)) ^ ((row&7)<<4);
}
// weight-frag read from slab: W[col][k-chunk lk], slot-XOR for bank spread
__device__ __forceinline__ bf16x8 rdW(const char* gb, int col, int lk){
    int slot = lk ^ ((col >> 1) & 3);
    return *(const bf16x8*)(gb + col*64 + slot*16);
}
// fully-linear slab staging: ws image -> LDS, contiguous on both sides
template<int N>
__device__ __forceinline__ void stage_lin(const ushort* src, char* dst, int w, int lane){
    #pragma unroll
    for (int i = 0; i < N; ++i) {
        __builtin_amdgcn_global_load_lds(
            (const __attribute__((address_space(1))) void*)(src + (size_t)(i*512 + w*64 + lane)*8),
            (__attribute__((address_space(3))) void*)(dst + i*8192 + w*1024),
            16, 0, 0);
    }
}
// one gate/layer fragment cluster: 4 col-frags x 2 row-frags (operand-swapped MFMA)
__device__ __forceinline__ void mm4(const char* gb, int colbase, int lr, int lk,
                                    bf16x8 a0, bf16x8 a1, f32x4 acc[2][4]){
    #pragma unroll
    for (int j = 0; j < 4; ++j) {
        bf16x8 wf = rdW(gb, colbase + j*16 + lr, lk);
        acc[0][j] = __builtin_amdgcn_mfma_f32_16x16x32_bf16(wf, a0, acc[0][j], 0,0,0);
        acc[1][j] = __builtin_amdgcn_mfma_f32_16x16x32_bf16(wf, a1, acc[1][j], 0,0,0);
    }
}

__global__ void prep_weights(const float* __restrict__ W_ih, const float* __restrict__ W_hh,
                             const float* __restrict__ W1, const float* __restrict__ W2,
                             const float* __restrict__ W3, ushort* __restrict__ ws)
{
    int id = blockIdx.x*256 + threadIdx.x;
    if (id >= W_TOTAL) return;
    float v = 0.0f;
    if (id < OFF_W1) {                       // GRU slabs: [gate][col][slot][e]
        int slab = id / GRU_SLAB, u = id % GRU_SLAB;
        int gate = u >> 13, u2 = u & 8191;
        int col = u2 >> 5, v5 = u2 & 31, slot = v5 >> 3, e = v5 & 7;
        int kq = slot ^ ((col >> 1) & 3);
        int k = slab*32 + kq*8 + e;
        int rowz = gate*256 + col;
        v = (k < 73) ? W_ih[rowz*73 + k] : ((k < 96) ? 0.0f : W_hh[rowz*256 + (k-96)]);
    } else if (id < OFF_W2) {                // W1: 8 x 16KB kb-slabs
        int t = id - OFF_W1, kb = t >> 13, u2 = t & 8191;
        int col = u2 >> 5, v5 = u2 & 31, slot = v5 >> 3, e = v5 & 7;
        int kq = slot ^ ((col >> 1) & 3);
        v = W1[col*256 + kb*32 + kq*8 + e];
    } else if (id < OFF_W3) {                // W2: 8 x 8KB kb-slabs (128 cols)
        int t = id - OFF_W2, kb = t >> 12, u2 = t & 4095;
        int col = u2 >> 5, v5 = u2 & 31, slot = v5 >> 3, e = v5 & 7;
        int kq = slot ^ ((col >> 1) & 3);
        v = W2[col*256 + kb*32 + kq*8 + e];
    } else {                                 // W3: 4 x 16KB kb-slabs, cols>=162 zero
        int t = id - OFF_W3, kb = t >> 13, u2 = t & 8191;
        int col = u2 >> 5, v5 = u2 & 31, slot = v5 >> 3, e = v5 & 7;
        int kq = slot ^ ((col >> 1) & 3);
        int k = kb*32 + kq*8 + e;
        v = (col < 162) ? W3[col*128 + k] : 0.0f;
    }
    ws[id] = f2bf(v);
}

__global__ __launch_bounds__(NTHR, 1) void knet_mfma(
    const float* __restrict__ meas, const float* __restrict__ mask,
    const float* __restrict__ dt,   const float* __restrict__ baselines,
    const float* __restrict__ x_prev, const float* __restrict__ hx,
    const float* __restrict__ b_ih, const float* __restrict__ b_hh,
    const float* __restrict__ ln_g, const float* __restrict__ ln_b,
    const float* __restrict__ b1,   const float* __restrict__ b2,
    const float* __restrict__ b3,
    const ushort* __restrict__ ws,
    float* __restrict__ out)
{
    extern __shared__ char smem[];
    ushort* Rbu  = (ushort*)(smem + LDS_RBF2);   // Rb then F2
    char*   Hb   = smem + LDS_HB;
    char*   STG  = smem + LDS_STG;
    float*  xmc  = (float*)(smem + LDS_XMC);
    float*  lnscr= (float*)(smem + LDS_LNS);

    const int tid  = threadIdx.x;
    const int w    = __builtin_amdgcn_readfirstlane(tid >> 6);
    const int nq   = w & 3;
    const int mh   = w >> 2;
    const int lane = tid & 63;
    const int lr   = lane & 15;
    const int lk   = lane >> 4;
    const int lk8  = lk * 8;
    const int row0 = blockIdx.x * ROWS;
    const int mrow = mh*32 + lr;
    float* hout = out + (size_t)B_TOTAL*6;

    // prologue: slab 0 -> buf0 (linear copy)
    stage_lin<6>(ws + OFF_GRU, STG, w, lane);

    // ====== coalesced input staging -> buf1 scratch (f32) ======
    float* scr = (float*)(STG + 49152);
    {
        const size_t m0 = (size_t)row0*27;
        for (int i = tid; i < 1728; i += NTHR) scr[i]        = meas[m0 + i];
        for (int i = tid; i < 1728; i += NTHR) scr[1728 + i] = mask[m0 + i];
        const size_t b0 = (size_t)row0*12;
        for (int i = tid; i < 768; i += NTHR)  scr[3456 + i] = baselines[b0 + i];
        if (tid < 384) scr[4224 + tid] = x_prev[(size_t)row0*6 + tid];
        if (tid < 64)  scr[4608 + tid] = dt[row0 + tid];
        const size_t hbase = (size_t)row0 * 256;
        #pragma unroll
        for (int ii = 0; ii < 4; ++ii) {
            int cid = tid + ii*NTHR;
            int r  = cid >> 5;
            int k0 = (cid & 31) << 3;
            const float4* p = (const float4*)(hx + hbase + (size_t)r*256 + k0);
            float4 u = p[0], v2 = p[1];
            bf16x8 o;
            o[0]=(short)f2bf(u.x);  o[1]=(short)f2bf(u.y);  o[2]=(short)f2bf(u.z);  o[3]=(short)f2bf(u.w);
            o[4]=(short)f2bf(v2.x); o[5]=(short)f2bf(v2.y); o[6]=(short)f2bf(v2.z); o[7]=(short)f2bf(v2.w);
            *(bf16x8*)(Hb + swzb(r, k0)) = o;
        }
    }
    __syncthreads();

    // ====== geometry from scratch -> Rb, xmc ======
    if (w < 4) {
        const int row = lane;
        const float dtv = scr[4608 + row];
        const float dts = dtv * NORM_R;
        float xp[6], xm[6];
        #pragma unroll
        for (int s = 0; s < 6; ++s) xp[s] = scr[4224 + row*6 + s];
        xm[0] = xp[0] + dts*xp[1]; xm[1] = xp[1];
        xm[2] = xp[2] + dts*xp[3]; xm[3] = xp[3];
        xm[4] = xp[4] + dts*xp[5]; xm[5] = xp[5];
        if (w < 3) {
            float xr[6];
            #pragma unroll
            for (int s = 0; s < 6; ++s) {
                float b = (w == 0) ? 0.0f : scr[3456 + row*12 + (w-1)*6 + s];
                xr[s] = xm[s] - b;
            }
            float rxy = sqrtf(xr[0]*xr[0] + xr[2]*xr[2] + 1e-9f);
            float azv = atan2f(xr[2], xr[0]) * (1.0f/PI_F);
            float elv = atan2f(xr[4], rxy)   * (1.0f/PI_F);
            float rrv = sqrtf(xr[0]*xr[0] + xr[2]*xr[2] + xr[4]*xr[4] + 1e-9f);
            float y[9] = {azv, elv, rrv, azv, elv, 0.0f, azv, 0.0f, 0.0f};
            const bool ang[9] = {true,true,false,true,true,false,true,false,false};
            #pragma unroll
            for (int i = 0; i < 9; ++i) {
                int m = w*9 + i;
                float ms = scr[1728 + row*27 + m];
                float v  = scr[row*27 + m] - y[i];
                if (ang[i]) v = v - 2.0f*rintf(v*0.5f);
                v *= ms;
                Rbu[row*104 + m]      = f2bf(v);
                Rbu[row*104 + 27 + m] = f2bf(ms);
            }
        } else {
            Rbu[row*104 + 54] = f2bf(dtv);
            #pragma unroll
            for (int s = 0; s < 6; ++s) Rbu[row*104 + 55 + s] = f2bf(xm[s]);
            #pragma unroll
            for (int q = 0; q < 12; ++q) Rbu[row*104 + 61 + q] = f2bf(scr[3456 + row*12 + q]);
            #pragma unroll
            for (int k = 73; k < 96; ++k) Rbu[row*104 + k] = 0;
            #pragma unroll
            for (int s = 0; s < 6; ++s) xmc[row*6 + s] = xm[s];
        }
    }
    __syncthreads();

    // ====== GRU: 11 x 48KB phases (r,z,n per phase; shared A-frags) ======
    f32x4 ar[2][4], az[2][4], agi[2][4], agh[2][4];
    #pragma unroll
    for (int i = 0; i < 2; ++i)
        #pragma unroll
        for (int j = 0; j < 4; ++j) {
            ar[i][j]=(f32x4){0,0,0,0}; az[i][j]=(f32x4){0,0,0,0};
            agi[i][j]=(f32x4){0,0,0,0}; agh[i][j]=(f32x4){0,0,0,0};
        }
    #pragma unroll
    for (int kb = 0; kb < 11; ++kb) {
        WAIT_VM0; BARv;
        if (kb < 10) stage_lin<6>(ws + OFF_GRU + (kb+1)*GRU_SLAB, STG + ((kb+1)&1)*49152, w, lane);
        else         stage_lin<6>(ws + OFF_W1,                    STG + 49152,            w, lane); // p11 -> buf1
        const char* sb = STG + (kb&1)*49152;
        bf16x8 a0, a1;
        if (kb < 3) { a0 = *(const bf16x8*)(Rbu + mrow*104 + kb*32 + lk8);
                      a1 = *(const bf16x8*)(Rbu + (mrow+16)*104 + kb*32 + lk8); }
        else        { a0 = *(const bf16x8*)(Hb + swzb(mrow,    (kb-3)*32 + lk8));
                      a1 = *(const bf16x8*)(Hb + swzb(mrow+16, (kb-3)*32 + lk8)); }
        __builtin_amdgcn_s_setprio(1);
        mm4(sb,         nq*64, lr, lk, a0, a1, ar);
        mm4(sb + 16384, nq*64, lr, lk, a0, a1, az);
        if (kb < 3) mm4(sb + 32768, nq*64, lr, lk, a0, a1, agi);
        else        mm4(sb + 32768, nq*64, lr, lk, a0, a1, agh);
        __builtin_amdgcn_s_setprio(0);
    }

    // ====== GRU epilogue: gates -> h_new (regs) + global store + LN partials ======
    f32x4 hnv[2][4];
    float lsum[2] = {0,0}, lsq[2] = {0,0};
    #pragma unroll
    for (int j = 0; j < 4; ++j) {
        const int c0 = nq*64 + j*16 + lk*4;
        f32x4 bir = *(const f32x4*)(b_ih + c0),        bhr = *(const f32x4*)(b_hh + c0);
        f32x4 biz = *(const f32x4*)(b_ih + 256 + c0),  bhz = *(const f32x4*)(b_hh + 256 + c0);
        f32x4 bin_= *(const f32x4*)(b_ih + 512 + c0),  bhn = *(const f32x4*)(b_hh + 512 + c0);
        #pragma unroll
        for (int i = 0; i < 2; ++i) {
            const int row = mh*32 + i*16 + lr;
            uint2 hxd = *(const uint2*)(Hb + swzb(row, c0));
            float hx_[4] = { b2f((ushort)(hxd.x & 0xffffu)), b2f((ushort)(hxd.x >> 16)),
                             b2f((ushort)(hxd.y & 0xffffu)), b2f((ushort)(hxd.y >> 16)) };
            f32x4 hn4;
            #pragma unroll
            for (int e = 0; e < 4; ++e) {
                float rg = sigm(ar[i][j][e] + bir[e] + bhr[e]);
                float zg = sigm(az[i][j][e] + biz[e] + bhz[e]);
                float ng = tanh_(agi[i][j][e] + bin_[e] + rg*(agh[i][j][e] + bhn[e]));
                float hn = (1.0f - zg)*ng + zg*hx_[e];
                hn4[e] = hn;
                lsum[i] += hn; lsq[i] += hn*hn;
            }
            hnv[i][j] = hn4;
            float4 st = { hn4[0], hn4[1], hn4[2], hn4[3] };
            *(float4*)(hout + (size_t)(row0+row)*256 + c0) = st;
        }
    }
    #pragma unroll
    for (int i = 0; i < 2; ++i) {
        lsum[i] += __shfl_xor(lsum[i], 16); lsum[i] += __shfl_xor(lsum[i], 32);
        lsq[i]  += __shfl_xor(lsq[i], 16);  lsq[i]  += __shfl_xor(lsq[i], 32);
    }
    if (lk == 0) {
        #pragma unroll
        for (int i = 0; i < 2; ++i) {
            const int row = mh*32 + i*16 + lr;
            lnscr[row*8 + nq*2 + 0] = lsum[i];
            lnscr[row*8 + nq*2 + 1] = lsq[i];
        }
    }
    __syncthreads();

    // ====== LayerNorm apply (regs -> Hb h_ln) ======
    {
        float mu[2], rstd[2];
        #pragma unroll
        for (int i = 0; i < 2; ++i) {
            const int row = mh*32 + i*16 + lr;
            float s = 0, q = 0;
            #pragma unroll
            for (int qq = 0; qq < 4; ++qq) { s += lnscr[row*8 + qq*2]; q += lnscr[row*8 + qq*2 + 1]; }
            mu[i] = s * (1.0f/256.0f);
            rstd[i] = rsqrtf(q*(1.0f/256.0f) - mu[i]*mu[i] + 1e-5f);
        }
        #pragma unroll
        for (int j = 0; j < 4; ++j) {
            const int c0 = nq*64 + j*16 + lk*4;
            f32x4 g4 = *(const f32x4*)(ln_g + c0);
            f32x4 b4 = *(const f32x4*)(ln_b + c0);
            #pragma unroll
            for (int i = 0; i < 2; ++i) {
                const int row = mh*32 + i*16 + lr;
                float v0 = (hnv[i][j][0]-mu[i])*rstd[i]*g4[0] + b4[0];
                float v1 = (hnv[i][j][1]-mu[i])*rstd[i]*g4[1] + b4[1];
                float v2 = (hnv[i][j][2]-mu[i])*rstd[i]*g4[2] + b4[2];
                float v3 = (hnv[i][j][3]-mu[i])*rstd[i]*g4[3] + b4[3];
                uint2 o;
                o.x = (unsigned)f2bf(v0) | ((unsigned)f2bf(v1) << 16);
                o.y = (unsigned)f2bf(v2) | ((unsigned)f2bf(v3) << 16);
                *(uint2*)(Hb + swzb(row, c0)) = o;
            }
        }
    }
    __syncthreads();

    // ====== f1 = relu(W1 h_ln + b1): 3 phases (kb 0-2, 3-5, 6-7) ======
    f32x4 c2[2][4];
    #pragma unroll
    for (int i = 0; i < 2; ++i)
        #pragma unroll
        for (int j = 0; j < 4; ++j) c2[i][j] = (f32x4){0,0,0,0};
    // p11 (buf1): kb 0..2
    WAIT_VM0; BARv;
    stage_lin<6>(ws + OFF_W1 + 3*8192, STG, w, lane);            // p12 -> buf0
    {
        const char* sb = STG + 49152;
        #pragma unroll
        for (int kb = 0; kb < 3; ++kb) {
            bf16x8 a0 = *(const bf16x8*)(Hb + swzb(mrow,    kb*32 + lk8));
            bf16x8 a1 = *(const bf16x8*)(Hb + swzb(mrow+16, kb*32 + lk8));
            __builtin_amdgcn_s_setprio(1);
            mm4(sb + kb*16384, nq*64, lr, lk, a0, a1, c2);
            __builtin_amdgcn_s_setprio(0);
        }
    }
    // p12 (buf0): kb 3..5
    WAIT_VM0; BARv;
    stage_lin<4>(ws + OFF_W1 + 6*8192, STG + 49152, w, lane);    // p13 -> buf1
    {
        const char* sb = STG;
        #pragma unroll
        for (int kb = 3; kb < 6; ++kb) {
            bf16x8 a0 = *(const bf16x8*)(Hb + swzb(mrow,    kb*32 + lk8));
            bf16x8 a1 = *(const bf16x8*)(Hb + swzb(mrow+16, kb*32 + lk8));
            __builtin_amdgcn_s_setprio(1);
            mm4(sb + (kb-3)*16384, nq*64, lr, lk, a0, a1, c2);
            __builtin_amdgcn_s_setprio(0);
        }
    }
    // p13 (buf1): kb 6..7
    WAIT_VM0; BARv;
    stage_lin<4>(ws + OFF_W2, STG, w, lane);                     // p14 -> buf0
    {
        const char* sb = STG + 49152;
        #pragma unroll
        for (int kb = 6; kb < 8; ++kb) {
            bf16x8 a0 = *(const bf16x8*)(Hb + swzb(mrow,    kb*32 + lk8));
            bf16x8 a1 = *(const bf16x8*)(Hb + swzb(mrow+16, kb*32 + lk8));
            __builtin_amdgcn_s_setprio(1);
            mm4(sb + (kb-6)*16384, nq*64, lr, lk, a0, a1, c2);
            __builtin_amdgcn_s_setprio(0);
        }
    }
    __syncthreads();   // all h_ln reads done before f1-act overwrite of Hb
    #pragma unroll
    for (int j = 0; j < 4; ++j) {
        const int c0 = nq*64 + j*16 + lk*4;
        f32x4 b4 = *(const f32x4*)(b1 + c0);
        #pragma unroll
        for (int i = 0; i < 2; ++i) {
            const int row = mh*32 + i*16 + lr;
            uint2 o;
            o.x = (unsigned)f2bf(fmaxf(c2[i][j][0]+b4[0],0.f)) | ((unsigned)f2bf(fmaxf(c2[i][j][1]+b4[1],0.f)) << 16);
            o.y = (unsigned)f2bf(fmaxf(c2[i][j][2]+b4[2],0.f)) | ((unsigned)f2bf(fmaxf(c2[i][j][3]+b4[3],0.f)) << 16);
            *(uint2*)(Hb + swzb(row, c0)) = o;
        }
    }
    __syncthreads();

    // ====== f2 = relu(W2 f1 + b2): 2 phases ======
    f32x4 c3[2][2];
    #pragma unroll
    for (int i = 0; i < 2; ++i)
        #pragma unroll
        for (int j = 0; j < 2; ++j) c3[i][j] = (f32x4){0,0,0,0};
    // p14 (buf0): kb 0..3
    WAIT_VM0; BARv;
    stage_lin<4>(ws + OFF_W2 + 4*4096, STG + 49152, w, lane);    // p15 -> buf1
    {
        const char* sb = STG;
        #pragma unroll
        for (int kb = 0; kb < 4; ++kb) {
            bf16x8 a0 = *(const bf16x8*)(Hb + swzb(mrow,    kb*32 + lk8));
            bf16x8 a1 = *(const bf16x8*)(Hb + swzb(mrow+16, kb*32 + lk8));
            __builtin_amdgcn_s_setprio(1);
            #pragma unroll
            for (int j = 0; j < 2; ++j) {
                bf16x8 wf = rdW(sb + kb*8192, nq*32 + j*16 + lr, lk);
                c3[0][j] = __builtin_amdgcn_mfma_f32_16x16x32_bf16(wf, a0, c3[0][j], 0,0,0);
                c3[1][j] = __builtin_amdgcn_mfma_f32_16x16x32_bf16(wf, a1, c3[1][j], 0,0,0);
            }
            __builtin_amdgcn_s_setprio(0);
        }
    }
    // p15 (buf1): kb 4..7
    WAIT_VM0; BARv;
    stage_lin<4>(ws + OFF_W3, STG, w, lane);                     // p16 -> buf0
    {
        const char* sb = STG + 49152;
        #pragma unroll
        for (int kb = 4; kb < 8; ++kb) {
            bf16x8 a0 = *(const bf16x8*)(Hb + swzb(mrow,    kb*32 + lk8));
            bf16x8 a1 = *(const bf16x8*)(Hb + swzb(mrow+16, kb*32 + lk8));
            __builtin_amdgcn_s_setprio(1);
            #pragma unroll
            for (int j = 0; j < 2; ++j) {
                bf16x8 wf = rdW(sb + (kb-4)*8192, nq*32 + j*16 + lr, lk);
                c3[0][j] = __builtin_amdgcn_mfma_f32_16x16x32_bf16(wf, a0, c3[0][j], 0,0,0);
                c3[1][j] = __builtin_amdgcn_mfma_f32_16x16x32_bf16(wf, a1, c3[1][j], 0,0,0);
            }
            __builtin_amdgcn_s_setprio(0);
        }
    }
    // preload innov for einsum (Rb dies to F2 overlay next)
    f32x4 iv[2][3];
    #pragma unroll
    for (int j = 0; j < 3; ++j) {
        #pragma unroll
        for (int i = 0; i < 2; ++i) {
            const int row = mh*32 + i*16 + lr;
            #pragma unroll
            for (int e = 0; e < 4; ++e) {
                int col = nq*48 + j*16 + lk*4 + e;
                int m = col - 27*(col/27);
                iv[i][j][e] = b2f(Rbu[row*104 + m]);
            }
        }
    }
    __syncthreads();   // innov reads done before F2 writes over Rb
    #pragma unroll
    for (int j = 0; j < 2; ++j) {
        const int c0 = nq*32 + j*16 + lk*4;
        f32x4 b4 = *(const f32x4*)(b2 + c0);
        #pragma unroll
        for (int i = 0; i < 2; ++i) {
            const int row = mh*32 + i*16 + lr;
            uint2 o;
            o.x = (unsigned)f2bf(fmaxf(c3[i][j][0]+b4[0],0.f)) | ((unsigned)f2bf(fmaxf(c3[i][j][1]+b4[1],0.f)) << 16);
            o.y = (unsigned)f2bf(fmaxf(c3[i][j][2]+b4[2],0.f)) | ((unsigned)f2bf(fmaxf(c3[i][j][3]+b4[3],0.f)) << 16);
            *(uint2*)((char*)Rbu + row*272 + c0*2) = o;      // F2 [64][136] u16
        }
    }
    __syncthreads();

    // ====== K = clip(W3 f2 + b3): 2 phases + einsum ======
    f32x4 c4[2][3];
    #pragma unroll
    for (int i = 0; i < 2; ++i)
        #pragma unroll
        for (int j = 0; j < 3; ++j) c4[i][j] = (f32x4){0,0,0,0};
    // p16 (buf0): kb 0,1
    WAIT_VM0; BARv;
    stage_lin<4>(ws + OFF_W3 + 2*8192, STG + 49152, w, lane);    // p17 -> buf1
    {
        const char* sb = STG;
        #pragma unroll
        for (int kb = 0; kb < 2; ++kb) {
            bf16x8 a0 = *(const bf16x8*)((char*)Rbu + (mrow     )*272 + (kb*32 + lk8)*2);
            bf16x8 a1 = *(const bf16x8*)((char*)Rbu + (mrow + 16)*272 + (kb*32 + lk8)*2);
            __builtin_amdgcn_s_setprio(1);
            #pragma unroll
            for (int j = 0; j < 3; ++j) {
                bf16x8 wf = rdW(sb + kb*16384, nq*48 + j*16 + lr, lk);
                c4[0][j] = __builtin_amdgcn_mfma_f32_16x16x32_bf16(wf, a0, c4[0][j], 0,0,0);
                c4[1][j] = __builtin_amdgcn_mfma_f32_16x16x32_bf16(wf, a1, c4[1][j], 0,0,0);
            }
            __builtin_amdgcn_s_setprio(0);
        }
    }
    // p17 (buf1): kb 2,3
    WAIT_VM0; BARv;
    {
        const char* sb = STG + 49152;
        #pragma unroll
        for (int kb = 2; kb < 4; ++kb) {
            bf16x8 a0 = *(const bf16x8*)((char*)Rbu + (mrow     )*272 + (kb*32 + lk8)*2);
            bf16x8 a1 = *(const bf16x8*)((char*)Rbu + (mrow + 16)*272 + (kb*32 + lk8)*2);
            __builtin_amdgcn_s_setprio(1);
            #pragma unroll
            for (int j = 0; j < 3; ++j) {
                bf16x8 wf = rdW(sb + (kb-2)*16384, nq*48 + j*16 + lr, lk);
                c4[0][j] = __builtin_amdgcn_mfma_f32_16x16x32_bf16(wf, a0, c4[0][j], 0,0,0);
                c4[1][j] = __builtin_amdgcn_mfma_f32_16x16x32_bf16(wf, a1, c4[1][j], 0,0,0);
            }
            __builtin_amdgcn_s_setprio(0);
        }
    }
    #pragma unroll
    for (int j = 0; j < 3; ++j) {
        #pragma unroll
        for (int i = 0; i < 2; ++i) {
            const int row = mh*32 + i*16 + lr;
            #pragma unroll
            for (int e = 0; e < 4; ++e) {
                int col = nq*48 + j*16 + lk*4 + e;
                if (col < 162) {
                    int s = col / 27;
                    float K = fminf(fmaxf(c4[i][j][e] + b3[col], -3.0f), 3.0f);
                    atomicAdd(&xmc[row*6 + s], K * iv[i][j][e]);
                }
            }
        }
    }
    __syncthreads();

    for (int t = tid; t < ROWS*6; t += NTHR) {
        int row = t / 6, s = t - row*6;
        float v = fminf(fmaxf(xmc[t], -5.0f), 5.0f);
        out[(size_t)(row0+row)*6 + s] = v;
    }
}

extern "C" void kernel_launch(void* const* d_in, const int* in_sizes, int n_in,
                              void* d_out, int out_size, void* d_ws, size_t ws_size,
                              hipStream_t stream) {
    const float* meas      = (const float*)d_in[0];
    const float* mask      = (const float*)d_in[1];
    const float* dtv       = (const float*)d_in[2];
    const float* baselines = (const float*)d_in[3];
    const float* x_prev    = (const float*)d_in[4];
    const float* hx        = (const float*)d_in[5];
    const float* W_ih      = (const float*)d_in[6];
    const float* W_hh      = (const float*)d_in[7];
    const float* b_ih      = (const float*)d_in[8];
    const float* b_hh      = (const float*)d_in[9];
    const float* ln_g      = (const float*)d_in[10];
    const float* ln_b      = (const float*)d_in[11];
    const float* W1        = (const float*)d_in[12];
    const float* b1        = (const float*)d_in[13];
    const float* W2        = (const float*)d_in[14];
    const float* b2        = (const float*)d_in[15];
    const float* W3        = (const float*)d_in[16];
    const float* b3        = (const float*)d_in[17];
    ushort* wsb = (ushort*)d_ws;
    float* outp = (float*)d_out;

    prep_weights<<<(W_TOTAL + 255)/256, 256, 0, stream>>>(W_ih, W_hh, W1, W2, W3, wsb);
    knet_mfma<<<NWG, NTHR, LDS_TOTAL, stream>>>(
        meas, mask, dtv, baselines, x_prev, hx,
        b_ih, b_hh, ln_g, ln_b, b1, b2, b3, wsb, outp);
}